// Round 11
// baseline (1755.661 us; speedup 1.0000x reference)
//
#include <hip/hip_runtime.h>
#include <hip/hip_bf16.h>

#define T_ 1024
#define B_ 64
#define H_ 128
#define G_ 512   // 4*H
#define E_ 128
#define V_ 32
#define N_ 8

// ---- cross-lane helpers (compile-time controls) ---------------------------
template<int CTRL>
__device__ __forceinline__ float dppf(float x) {
    return __int_as_float(__builtin_amdgcn_update_dpp(0, __float_as_int(x), CTRL, 0xF, 0xF, true));
}
template<int CTRL>
__device__ __forceinline__ int dppi(int x) {
    return __builtin_amdgcn_update_dpp(0, x, CTRL, 0xF, 0xF, true);
}
template<int OFF>
__device__ __forceinline__ float swzf(float x) {
    return __int_as_float(__builtin_amdgcn_ds_swizzle(__float_as_int(x), OFF));
}
template<int OFF>
__device__ __forceinline__ int swzi(int x) {
    return __builtin_amdgcn_ds_swizzle(x, OFF);
}
// DPP ctrl constants: quad_perm[a,b,c,d] = a|b<<2|c<<4|d<<6
#define QP_XOR1 0xB1   // [1,0,3,2]
#define QP_XOR2 0x4E   // [2,3,0,1]
#define QP_BC0  0x00
#define QP_BC1  0x55
#define QP_BC2  0xAA
#define QP_BC3  0xFF
#define ROW_ROR8 0x128 // row_ror:8 == xor8 within 16-row (for sums)
// ds_swizzle BitMode: (xor<<10)|(or<<5)|and
#define SWZ_XOR4  0x101F
#define SWZ_XOR16 0x401F

// W lives in AGPRs. PIN (volatile, once) establishes residency; RD is a
// NON-VOLATILE v_accvgpr_read — freely schedulable, so the 4 gate chains
// interleave and the read latency (~4-8 cyc, full-rate) hides.
// Round 8 proved "+a" pinning holds W in AGPRs (VGPR 88->96, no scratch);
// its 1539us regression was the VOLATILE reads serializing 128 read+FMA
// pairs. Round 9 proved plain VALU can't source AGPRs, so explicit reads
// are structural. Rounds 3-7/10 (no pins): compiler scratch-spills W and
// reloads via ~200-cyc buffer_loads each step = the 1035us / VALUBusy-37%.
#define RD(d, s) asm("v_accvgpr_read_b32 %0, %1" : "=v"(d) : "a"(s))
#define PIN8A(A, b_) asm volatile("" : "+a"(A[(b_)+0]), "+a"(A[(b_)+1]), \
    "+a"(A[(b_)+2]), "+a"(A[(b_)+3]), "+a"(A[(b_)+4]), "+a"(A[(b_)+5]), \
    "+a"(A[(b_)+6]), "+a"(A[(b_)+7]))

// LDS-only barrier (round 10: proven equal-perf and correct; keeps the
// global store/prefetch out of the barrier drain).
__device__ __forceinline__ void barrier_lds_only() {
    asm volatile("s_waitcnt lgkmcnt(0)" ::: "memory");
    __builtin_amdgcn_s_barrier();
    asm volatile("" ::: "memory");
}

// ---------------------------------------------------------------------------
// K0: proj[dir][v][g] = b_dir[g] + sum_e W_ih_dir[g][e] * emb[v][e]
// ---------------------------------------------------------------------------
__global__ __launch_bounds__(512) void proj_kernel(
    const float* __restrict__ emb,
    const float* __restrict__ Wih_f, const float* __restrict__ b_f,
    const float* __restrict__ Wih_b, const float* __restrict__ b_b,
    float* __restrict__ proj)
{
    int wg  = blockIdx.x;
    int dir = wg >> 5;
    int v   = wg & 31;
    const float* W    = dir ? Wih_b : Wih_f;
    const float* bias = dir ? b_b   : b_f;
    int tid = threadIdx.x;

    __shared__ float4 e_l[E_ / 4];
    if (tid < E_ / 4) e_l[tid] = ((const float4*)(emb + (size_t)v * E_))[tid];
    __syncthreads();

    float acc = bias[tid];
    const float4* wr = (const float4*)(W + (size_t)tid * E_);
#pragma unroll
    for (int k = 0; k < 32; ++k) {
        float4 wv = wr[k], ev = e_l[k];
        acc += wv.x * ev.x;
        acc += wv.y * ev.y;
        acc += wv.z * ev.z;
        acc += wv.w * ev.w;
    }
    proj[((size_t)dir * V_ + v) * G_ + tid] = acc;
}

// ---------------------------------------------------------------------------
// K1: per-(dir,batch) LSTM chain + fused FC.  [round-8 structure; RD now
// NON-volatile so the scheduler interleaves the 4 gate chains]
// grid 128, block 512. Thread (j=tid>>2, q=tid&3) holds chunk q (32 floats)
// of all 4 gate rows of j in 128 pinned AGPRs.
// ---------------------------------------------------------------------------
__global__ __launch_bounds__(512)
__attribute__((amdgpu_waves_per_eu(2, 2)))
void lstm_kernel(
    const int*   __restrict__ x,
    const float* __restrict__ Whh_f, const float* __restrict__ Whh_b,
    const float* __restrict__ proj,   // [2][V][G]
    const float* __restrict__ fcW,    // [8][256]
    float* __restrict__ part)         // [2][T][B][8]
{
    int wg  = blockIdx.x;
    int dir = wg >> 6;
    int b   = wg & 63;
    int tid = threadIdx.x;
    int j   = tid >> 2;
    int q   = tid & 3;
    int nw  = tid >> 6;     // FC output index (wave id)
    int e   = tid & 63;     // FC element pair index

    __shared__ float  w_stage[20480];   // 80 KB: W staging + occupancy forcer
    __shared__ int    tok_l[T_];        // 4 KB
    __shared__ float4 hb4[2][H_ / 4];   // double-buffered h

    for (int s = tid; s < T_; s += 512) tok_l[s] = x[(size_t)b * T_ + s];
    if (tid < H_) ((float*)hb4[0])[tid] = 0.f;

    float fw0 = fcW[nw * 256 + dir * H_ + 2 * e];
    float fw1 = fcW[nw * 256 + dir * H_ + 2 * e + 1];

    const float* Whh = dir ? Whh_b : Whh_f;

    // Stage gate r (64 KB) into LDS, read own chunk into wreg[r], pin into
    // AGPRs, then overwrite the stage with gate r+1 (kills rematerialization).
    // wreg[r][4k+m] = W_hh[r*128+j][ q*32 + ((k+2q)&7)*4 + m ]
    float wreg[4][32];
#pragma unroll
    for (int r = 0; r < 4; ++r) {
        const float4* Wg4 = (const float4*)(Whh + (size_t)r * H_ * H_);
        float4* st4 = (float4*)w_stage;
        for (int idx = tid; idx < (H_ * H_) / 4; idx += 512) st4[idx] = Wg4[idx];
        __syncthreads();
        const float4* myrow = (const float4*)(w_stage + j * H_ + q * 32);
#pragma unroll
        for (int k = 0; k < 8; ++k) {
            float4 v = myrow[(k + 2 * q) & 7];
            wreg[r][4 * k + 0] = v.x;
            wreg[r][4 * k + 1] = v.y;
            wreg[r][4 * k + 2] = v.z;
            wreg[r][4 * k + 3] = v.w;
        }
        PIN8A(wreg[r], 0); PIN8A(wreg[r], 8);
        PIN8A(wreg[r], 16); PIN8A(wreg[r], 24);
        __syncthreads();   // WAR: next r overwrites w_stage
    }
    asm volatile("" : "+v"(fw0), "+v"(fw1));

    const float* projd = proj + (size_t)dir * (V_ * G_);
    int gown = q * H_ + j;          // own gate row in proj
    float c = 0.f;

    float pv_c = projd[tok_l[dir ? (T_ - 1) : 0] * G_ + gown];

    // non-volatile read + FMA; accumulation order identical to rounds 6-8
#define MV1(r, acc, cmp, i4) { float t_; RD(t_, wreg[r][i4]); acc += t_ * hv.cmp; }
#define MVK(k) { \
    float4 hv = hb[q * 8 + (((k) + 2 * q) & 7)]; \
    MV1(0, a0, x, 4*(k)+0) MV1(0, a0, y, 4*(k)+1) MV1(0, a0, z, 4*(k)+2) MV1(0, a0, w, 4*(k)+3) \
    MV1(1, a1, x, 4*(k)+0) MV1(1, a1, y, 4*(k)+1) MV1(1, a1, z, 4*(k)+2) MV1(1, a1, w, 4*(k)+3) \
    MV1(2, a2, x, 4*(k)+0) MV1(2, a2, y, 4*(k)+1) MV1(2, a2, z, 4*(k)+2) MV1(2, a2, w, 4*(k)+3) \
    MV1(3, a3, x, 4*(k)+0) MV1(3, a3, y, 4*(k)+1) MV1(3, a3, z, 4*(k)+2) MV1(3, a3, w, 4*(k)+3) }

    int cur = 0;
    for (int t = 0; t < T_; ++t) {
        int tt = dir ? (T_ - 1 - t) : t;
        int tn = (t + 1 < T_) ? (t + 1) : t;
        float pv_n = projd[tok_l[dir ? (T_ - 1 - tn) : tn] * G_ + gown];

        const float4* hb = (const float4*)hb4[cur];
        float a0 = 0.f, a1 = 0.f, a2 = 0.f, a3 = 0.f;
        MVK(0) MVK(1) MVK(2) MVK(3) MVK(4) MVK(5) MVK(6) MVK(7)

        // quad reduce via DPP (bit-identical to shfl_xor 1,2)
        a0 += dppf<QP_XOR1>(a0); a0 += dppf<QP_XOR2>(a0);
        a1 += dppf<QP_XOR1>(a1); a1 += dppf<QP_XOR2>(a1);
        a2 += dppf<QP_XOR1>(a2); a2 += dppf<QP_XOR2>(a2);
        a3 += dppf<QP_XOR1>(a3); a3 += dppf<QP_XOR2>(a3);

        float tot = (q == 0) ? a0 : (q == 1) ? a1 : (q == 2) ? a2 : a3;
        tot += pv_c;
        float act = (q == 2) ? tanhf(tot) : 1.f / (1.f + expf(-tot));

        // gather quad activations via DPP broadcasts
        float gi = dppf<QP_BC0>(act);
        float gf = dppf<QP_BC1>(act);
        float gg = dppf<QP_BC2>(act);
        float go = dppf<QP_BC3>(act);

        c = gf * c + gi * gg;
        float h = go * tanhf(c);
        if (q == 0) ((float*)hb4[cur ^ 1])[j] = h;
        barrier_lds_only();                // LDS-only drain (round 10)

        // FC: wave nw computes logit nw; each lane dots 2 h elements
        float2 h2 = ((const float2*)hb4[cur ^ 1])[e];
        float p = fw0 * h2.x + fw1 * h2.y;
        p += dppf<QP_XOR1>(p);
        p += dppf<QP_XOR2>(p);
        p += swzf<SWZ_XOR4>(p);
        p += dppf<ROW_ROR8>(p);
        p += swzf<SWZ_XOR16>(p);
        float psum = p + __int_as_float(__builtin_amdgcn_readlane(__float_as_int(p), 32));
        if (e == 0) part[(((size_t)dir * T_ + tt) * B_ + b) * N_ + nw] = psum;

        pv_c = pv_n;
        cur ^= 1;
    }
#undef MV1
#undef MVK
}

// ---------------------------------------------------------------------------
// K2: Viterbi — round-3/6/7/8/10 alternating-layout version VERBATIM.
// ---------------------------------------------------------------------------
__global__ __launch_bounds__(64) void viterbi_kernel(
    const float* __restrict__ part,   // [2][T][B][8]
    const float* __restrict__ fc_b,
    const float* __restrict__ start_t,
    const float* __restrict__ end_t,
    const float* __restrict__ trans,  // [8][8]
    int* __restrict__ out)            // [B][T]
{
    int b = blockIdx.x;
    int l = threadIdx.x;
    int lo = l & 7, hi = l >> 3;

    __shared__ unsigned int hist_l[T_];

    float trA  = trans[lo * 8 + hi];   // style A: i=lo, j=hi
    float trB  = trans[hi * 8 + lo];   // style B: i=hi, j=lo
    float fcbA = fc_b[hi];
    float fcbB = fc_b[lo];
    const float* pf = part;
    const float* pb = part + (size_t)T_ * B_ * N_;

#define TSEL(ov, oi) { if ((ov) > v || ((ov) == v && (oi) < idx)) { v = (ov); idx = (oi); } }

#define VSTEPA(emval, tcur) { \
    float v = (score + trA) + (emval); int idx = lo; \
    { float ov = dppf<QP_XOR1>(v); int oi = dppi<QP_XOR1>(idx); TSEL(ov, oi) } \
    { float ov = dppf<QP_XOR2>(v); int oi = dppi<QP_XOR2>(idx); TSEL(ov, oi) } \
    { float ov = swzf<SWZ_XOR4>(v); int oi = swzi<SWZ_XOR4>(idx); TSEL(ov, oi) } \
    score = v; \
    unsigned pk = 0; \
    _Pragma("unroll") \
    for (int jj = 0; jj < 8; ++jj) \
        pk |= (unsigned)(__builtin_amdgcn_readlane(idx, 8 * jj) & 7) << (3 * jj); \
    if (l == 0) hist_l[tcur] = pk; }

#define VSTEPB(emval, tcur) { \
    float v = (score + trB) + (emval); int idx = hi; \
    { float ov = dppf<ROW_ROR8>(v); int oi = dppi<ROW_ROR8>(idx); TSEL(ov, oi) } \
    { float ov = swzf<SWZ_XOR16>(v); int oi = swzi<SWZ_XOR16>(idx); TSEL(ov, oi) } \
    { float ov = __shfl_xor(v, 32); int oi = __shfl_xor(idx, 32); TSEL(ov, oi) } \
    score = v; \
    unsigned pk = 0; \
    _Pragma("unroll") \
    for (int jj = 0; jj < 8; ++jj) \
        pk |= (unsigned)(__builtin_amdgcn_readlane(idx, jj) & 7) << (3 * jj); \
    if (l == 0) hist_l[tcur] = pk; }

#define LOADSUB(dst, ss) { \
    int t0_ = (ss) * 8; \
    _Pragma("unroll") \
    for (int p = 0; p < 8; ++p) { \
        int t_ = t0_ + p; \
        int jsel = (p & 1) ? hi : lo; \
        float fcbs = (p & 1) ? fcbA : fcbB; \
        size_t base = ((size_t)t_ * B_ + b) * N_ + jsel; \
        dst[p] = (pf[base] + pb[base]) + fcbs; } }

#define PROC8(arr, t0_) { \
    VSTEPB(arr[0], (t0_) + 0) VSTEPA(arr[1], (t0_) + 1) \
    VSTEPB(arr[2], (t0_) + 2) VSTEPA(arr[3], (t0_) + 3) \
    VSTEPB(arr[4], (t0_) + 4) VSTEPA(arr[5], (t0_) + 5) \
    VSTEPB(arr[6], (t0_) + 6) VSTEPA(arr[7], (t0_) + 7) }

    float emA[8], emB[8];
    float score;

    LOADSUB(emA, 0)
    LOADSUB(emB, 1)
    score = start_t[lo] + emA[0];
    VSTEPA(emA[1], 1) VSTEPB(emA[2], 2) VSTEPA(emA[3], 3) VSTEPB(emA[4], 4)
    VSTEPA(emA[5], 5) VSTEPB(emA[6], 6) VSTEPA(emA[7], 7)

    for (int s = 1; s < 127; s += 2) {
        LOADSUB(emA, s + 1)
        PROC8(emB, s * 8)
        LOADSUB(emB, s + 2)
        PROC8(emA, (s + 1) * 8)
    }
    PROC8(emB, 127 * 8)

    score += end_t[hi];
    int tag;
    {
        float v = score; int idx = hi;
        { float ov = dppf<ROW_ROR8>(v); int oi = dppi<ROW_ROR8>(idx); TSEL(ov, oi) }
        { float ov = swzf<SWZ_XOR16>(v); int oi = swzi<SWZ_XOR16>(idx); TSEL(ov, oi) }
        { float ov = __shfl_xor(v, 32); int oi = __shfl_xor(idx, 32); TSEL(ov, oi) }
        tag = idx;
    }
    if (l == 0) out[(size_t)b * T_ + (T_ - 1)] = tag;
    __syncthreads();

    for (int t0b = T_ - 16; t0b >= 0; t0b -= 16) {
        unsigned int pk[16];
#pragma unroll
        for (int qq = 0; qq < 16; ++qq) pk[qq] = hist_l[t0b + qq];
#pragma unroll
        for (int qq = 15; qq >= 0; --qq) {
            int t = t0b + qq;
            if (t >= 1) {
                tag = (pk[qq] >> (3 * tag)) & 7;
                if (l == 0) out[(size_t)b * T_ + t - 1] = tag;
            }
        }
    }
#undef TSEL
#undef VSTEPA
#undef VSTEPB
#undef LOADSUB
#undef PROC8
}

extern "C" void kernel_launch(void* const* d_in, const int* in_sizes, int n_in,
                              void* d_out, int out_size, void* d_ws, size_t ws_size,
                              hipStream_t stream) {
    (void)in_sizes; (void)n_in; (void)out_size; (void)ws_size;
    const int*   x      = (const int*)  d_in[0];
    const float* emb    = (const float*)d_in[1];
    const float* Wih_f  = (const float*)d_in[2];
    const float* Whh_f  = (const float*)d_in[3];
    const float* b_f    = (const float*)d_in[4];
    const float* Wih_b  = (const float*)d_in[5];
    const float* Whh_b  = (const float*)d_in[6];
    const float* b_b    = (const float*)d_in[7];
    const float* fcW    = (const float*)d_in[8];
    const float* fcb    = (const float*)d_in[9];
    const float* startt = (const float*)d_in[10];
    const float* endt   = (const float*)d_in[11];
    const float* trans  = (const float*)d_in[12];

    float* proj = (float*)d_ws;                    // 2*32*512 floats = 128 KB
    float* part = proj + 2 * V_ * G_;              // 2*1024*64*8 floats = 4 MB
    int*   out  = (int*)d_out;

    proj_kernel<<<64, 512, 0, stream>>>(emb, Wih_f, b_f, Wih_b, b_b, proj);
    lstm_kernel<<<128, 512, 0, stream>>>(x, Whh_f, Whh_b, proj, fcW, part);
    viterbi_kernel<<<64, 64, 0, stream>>>(part, fcb, startt, endt, trans, out);
}

// Round 12
// 1272.056 us; speedup vs baseline: 1.3802x; 1.3802x over previous
//
#include <hip/hip_runtime.h>
#include <hip/hip_bf16.h>

#define T_ 1024
#define B_ 64
#define H_ 128
#define G_ 512   // 4*H
#define E_ 128
#define V_ 32
#define N_ 8

// ---- cross-lane helpers (compile-time controls) ---------------------------
template<int CTRL>
__device__ __forceinline__ float dppf(float x) {
    return __int_as_float(__builtin_amdgcn_update_dpp(0, __float_as_int(x), CTRL, 0xF, 0xF, true));
}
template<int CTRL>
__device__ __forceinline__ int dppi(int x) {
    return __builtin_amdgcn_update_dpp(0, x, CTRL, 0xF, 0xF, true);
}
template<int OFF>
__device__ __forceinline__ float swzf(float x) {
    return __int_as_float(__builtin_amdgcn_ds_swizzle(__float_as_int(x), OFF));
}
template<int OFF>
__device__ __forceinline__ int swzi(int x) {
    return __builtin_amdgcn_ds_swizzle(x, OFF);
}
// DPP ctrl constants: quad_perm[a,b,c,d] = a|b<<2|c<<4|d<<6
#define QP_XOR1 0xB1   // [1,0,3,2]
#define QP_XOR2 0x4E   // [2,3,0,1]
#define QP_BC0  0x00
#define QP_BC1  0x55
#define QP_BC2  0xAA
#define QP_BC3  0xFF
#define ROW_ROR8 0x128 // row_ror:8 == xor8 within 16-row (for sums)
// ds_swizzle BitMode: (xor<<10)|(or<<5)|and
#define SWZ_XOR4  0x101F
#define SWZ_XOR16 0x401F

// ---------------------------------------------------------------------------
// K0: proj[dir][v][g] = b_dir[g] + sum_e W_ih_dir[g][e] * emb[v][e]
// ---------------------------------------------------------------------------
__global__ __launch_bounds__(512) void proj_kernel(
    const float* __restrict__ emb,
    const float* __restrict__ Wih_f, const float* __restrict__ b_f,
    const float* __restrict__ Wih_b, const float* __restrict__ b_b,
    float* __restrict__ proj)
{
    int wg  = blockIdx.x;
    int dir = wg >> 5;
    int v   = wg & 31;
    const float* W    = dir ? Wih_b : Wih_f;
    const float* bias = dir ? b_b   : b_f;
    int tid = threadIdx.x;

    __shared__ float4 e_l[E_ / 4];
    if (tid < E_ / 4) e_l[tid] = ((const float4*)(emb + (size_t)v * E_))[tid];
    __syncthreads();

    float acc = bias[tid];
    const float4* wr = (const float4*)(W + (size_t)tid * E_);
#pragma unroll
    for (int k = 0; k < 32; ++k) {
        float4 wv = wr[k], ev = e_l[k];
        acc += wv.x * ev.x;
        acc += wv.y * ev.y;
        acc += wv.z * ev.z;
        acc += wv.w * ev.w;
    }
    proj[((size_t)dir * V_ + v) * G_ + tid] = acc;
}

// ---------------------------------------------------------------------------
// K1: per-(dir,batch) LSTM chain + fused FC.  [1024-thread layout: 64 W
// floats/thread — half of rounds 3-11's 128]
// grid 128, block 1024. Thread (j=tid>>3, q=tid&7): gate pair p=q&1 (rows
// 2p,2p+1), h-chunk c=q>>1 (32 floats). Per-thread W = 64 floats + ~36
// working ~= 100 VGPR, under the 128 budget at the LDS-forced 4 waves/SIMD.
// Rationale: rounds 3-11 proved the allocator refuses >~88 VGPRs of live
// state and scratch-spills the rest; at 128 W floats/thread that reload is
// 256KB/block/step = per-XCD-L2-BW-bound = 1035us. Halving the footprint
// either goes resident (issue-bound ~450-650us) or spills 4x less.
// Gate mapping (re-derived line-by-line this round): quad positions
// {0,1,2,3} hold gates {i,g,f,o}; reduce XOR2(c^1)+XOR4(c^2); single
// barrier with double-buffered h.
// ---------------------------------------------------------------------------
__global__ __launch_bounds__(1024)
__attribute__((amdgpu_waves_per_eu(4, 4)))
void lstm_kernel(
    const int*   __restrict__ x,
    const float* __restrict__ Whh_f, const float* __restrict__ Whh_b,
    const float* __restrict__ proj,   // [2][V][G]
    const float* __restrict__ fcW,    // [8][256]
    float* __restrict__ part)         // [2][T][B][8]
{
    int wg  = blockIdx.x;
    int dir = wg >> 6;
    int b   = wg & 63;
    int tid = threadIdx.x;
    int j   = tid >> 3;        // 0..127
    int q   = tid & 7;
    int p   = q & 1;           // gate pair -> rows {2p, 2p+1}
    int c   = q >> 1;          // h-chunk 0..3
    int which = c & 1;         // own gate within pair
    int gate_own = 2 * p + which;   // quad positions {0,1,2,3} -> gates {0,2,1,3}

    __shared__ union { int tok[T_]; char pad[83 * 1024]; } tu;  // 1-block/CU forcer
    __shared__ float4 hb4[2][H_ / 4];   // double-buffered h

    tu.tok[tid] = x[(size_t)b * T_ + tid];
    if (tid < H_) ((float*)hb4[0])[tid] = 0.f;

    int nw = tid >> 6;      // FC logit (waves 0-7)
    int e  = tid & 63;      // FC element pair
    float fw0 = 0.f, fw1 = 0.f;
    if (tid < 512) {
        fw0 = fcW[nw * 256 + dir * H_ + 2 * e];
        fw1 = fcW[nw * 256 + dir * H_ + 2 * e + 1];
    }

    const float* Whh = dir ? Whh_b : Whh_f;

    // w0/w1[k] = W_hh[(row)*128+j][ c*32 + ((k+2c)&7)*4 .. +4 )  (rotation at
    // load keeps register index compile-time; bank-spreads the h-reads)
    float4 w0[8], w1[8];
    {
        const float4* wr0 = (const float4*)(Whh + (size_t)((2 * p) * H_ + j) * H_ + c * 32);
        const float4* wr1 = (const float4*)(Whh + (size_t)((2 * p + 1) * H_ + j) * H_ + c * 32);
#pragma unroll
        for (int k = 0; k < 8; ++k) {
            w0[k] = wr0[(k + 2 * c) & 7];
            w1[k] = wr1[(k + 2 * c) & 7];
        }
    }
#pragma unroll
    for (int k = 0; k < 8; ++k) {
        asm volatile("" : "+v"(w0[k].x), "+v"(w0[k].y), "+v"(w0[k].z), "+v"(w0[k].w));
        asm volatile("" : "+v"(w1[k].x), "+v"(w1[k].y), "+v"(w1[k].z), "+v"(w1[k].w));
    }
    asm volatile("" : "+v"(fw0), "+v"(fw1));

    const float* projd = proj + (size_t)dir * (V_ * G_);
    int gown = gate_own * H_ + j;
    float cc = 0.f;
    __syncthreads();

    float pv_c = projd[tu.tok[dir ? (T_ - 1) : 0] * G_ + gown];

    int cur = 0;
    for (int t = 0; t < T_; ++t) {
        int tt = dir ? (T_ - 1 - t) : t;
        int tn = (t + 1 < T_) ? (t + 1) : t;
        float pv_n = projd[tu.tok[dir ? (T_ - 1 - tn) : tn] * G_ + gown];

        const float4* hb = (const float4*)hb4[cur];
        float a0 = 0.f, a1 = 0.f;
#pragma unroll
        for (int k = 0; k < 8; ++k) {
            float4 hv = hb[c * 8 + ((k + 2 * c) & 7)];
            float4 u0 = w0[k], u1 = w1[k];
            a0 += u0.x * hv.x; a0 += u0.y * hv.y; a0 += u0.z * hv.z; a0 += u0.w * hv.w;
            a1 += u1.x * hv.x; a1 += u1.y * hv.y; a1 += u1.z * hv.z; a1 += u1.w * hv.w;
        }
        // combine the 4 chunks (lanes q, q^2 via DPP quad_perm XOR2; q^4 via
        // ds_swizzle XOR4) — same xor-tree summation as all passing rounds
        a0 += dppf<QP_XOR2>(a0);
        a1 += dppf<QP_XOR2>(a1);
        a0 += swzf<SWZ_XOR4>(a0);
        a1 += swzf<SWZ_XOR4>(a1);

        float tot = which ? a1 : a0;
        tot += pv_c;
        float act = (gate_own == 2) ? tanhf(tot) : 1.f / (1.f + expf(-tot));

        // quad positions {0,1,2,3} hold gates {i,g,f,o} -> broadcast-gather
        float gi = dppf<QP_BC0>(act);
        float gg = dppf<QP_BC1>(act);
        float gf = dppf<QP_BC2>(act);
        float go = dppf<QP_BC3>(act);

        cc = gf * cc + gi * gg;
        float h = go * tanhf(cc);
        if (q == 0) ((float*)hb4[cur ^ 1])[j] = h;
        __syncthreads();                   // single barrier per step

        // FC on waves 0-7: wave nw computes logit nw (2 FMA + butterfly)
        if (tid < 512) {
            float2 h2 = ((const float2*)hb4[cur ^ 1])[e];
            float pa = fw0 * h2.x + fw1 * h2.y;
            pa += dppf<QP_XOR1>(pa);
            pa += dppf<QP_XOR2>(pa);
            pa += swzf<SWZ_XOR4>(pa);
            pa += dppf<ROW_ROR8>(pa);
            pa += swzf<SWZ_XOR16>(pa);
            float psum = pa + __int_as_float(__builtin_amdgcn_readlane(__float_as_int(pa), 32));
            if (e == 0) part[(((size_t)dir * T_ + tt) * B_ + b) * N_ + nw] = psum;
        }
        pv_c = pv_n;
        cur ^= 1;
    }
}

// ---------------------------------------------------------------------------
// K2: Viterbi — round-3/6/7/10/11 alternating-layout version VERBATIM
// (passing, absmax 0 in four separate benches).
// ---------------------------------------------------------------------------
__global__ __launch_bounds__(64) void viterbi_kernel(
    const float* __restrict__ part,   // [2][T][B][8]
    const float* __restrict__ fc_b,
    const float* __restrict__ start_t,
    const float* __restrict__ end_t,
    const float* __restrict__ trans,  // [8][8]
    int* __restrict__ out)            // [B][T]
{
    int b = blockIdx.x;
    int l = threadIdx.x;
    int lo = l & 7, hi = l >> 3;

    __shared__ unsigned int hist_l[T_];

    float trA  = trans[lo * 8 + hi];   // style A: i=lo, j=hi
    float trB  = trans[hi * 8 + lo];   // style B: i=hi, j=lo
    float fcbA = fc_b[hi];
    float fcbB = fc_b[lo];
    const float* pf = part;
    const float* pb = part + (size_t)T_ * B_ * N_;

#define TSEL(ov, oi) { if ((ov) > v || ((ov) == v && (oi) < idx)) { v = (ov); idx = (oi); } }

#define VSTEPA(emval, tcur) { \
    float v = (score + trA) + (emval); int idx = lo; \
    { float ov = dppf<QP_XOR1>(v); int oi = dppi<QP_XOR1>(idx); TSEL(ov, oi) } \
    { float ov = dppf<QP_XOR2>(v); int oi = dppi<QP_XOR2>(idx); TSEL(ov, oi) } \
    { float ov = swzf<SWZ_XOR4>(v); int oi = swzi<SWZ_XOR4>(idx); TSEL(ov, oi) } \
    score = v; \
    unsigned pk = 0; \
    _Pragma("unroll") \
    for (int jj = 0; jj < 8; ++jj) \
        pk |= (unsigned)(__builtin_amdgcn_readlane(idx, 8 * jj) & 7) << (3 * jj); \
    if (l == 0) hist_l[tcur] = pk; }

#define VSTEPB(emval, tcur) { \
    float v = (score + trB) + (emval); int idx = hi; \
    { float ov = dppf<ROW_ROR8>(v); int oi = dppi<ROW_ROR8>(idx); TSEL(ov, oi) } \
    { float ov = swzf<SWZ_XOR16>(v); int oi = swzi<SWZ_XOR16>(idx); TSEL(ov, oi) } \
    { float ov = __shfl_xor(v, 32); int oi = __shfl_xor(idx, 32); TSEL(ov, oi) } \
    score = v; \
    unsigned pk = 0; \
    _Pragma("unroll") \
    for (int jj = 0; jj < 8; ++jj) \
        pk |= (unsigned)(__builtin_amdgcn_readlane(idx, jj) & 7) << (3 * jj); \
    if (l == 0) hist_l[tcur] = pk; }

#define LOADSUB(dst, ss) { \
    int t0_ = (ss) * 8; \
    _Pragma("unroll") \
    for (int p = 0; p < 8; ++p) { \
        int t_ = t0_ + p; \
        int jsel = (p & 1) ? hi : lo; \
        float fcbs = (p & 1) ? fcbA : fcbB; \
        size_t base = ((size_t)t_ * B_ + b) * N_ + jsel; \
        dst[p] = (pf[base] + pb[base]) + fcbs; } }

#define PROC8(arr, t0_) { \
    VSTEPB(arr[0], (t0_) + 0) VSTEPA(arr[1], (t0_) + 1) \
    VSTEPB(arr[2], (t0_) + 2) VSTEPA(arr[3], (t0_) + 3) \
    VSTEPB(arr[4], (t0_) + 4) VSTEPA(arr[5], (t0_) + 5) \
    VSTEPB(arr[6], (t0_) + 6) VSTEPA(arr[7], (t0_) + 7) }

    float emA[8], emB[8];
    float score;

    LOADSUB(emA, 0)
    LOADSUB(emB, 1)
    score = start_t[lo] + emA[0];
    VSTEPA(emA[1], 1) VSTEPB(emA[2], 2) VSTEPA(emA[3], 3) VSTEPB(emA[4], 4)
    VSTEPA(emA[5], 5) VSTEPB(emA[6], 6) VSTEPA(emA[7], 7)

    for (int s = 1; s < 127; s += 2) {
        LOADSUB(emA, s + 1)
        PROC8(emB, s * 8)
        LOADSUB(emB, s + 2)
        PROC8(emA, (s + 1) * 8)
    }
    PROC8(emB, 127 * 8)

    score += end_t[hi];
    int tag;
    {
        float v = score; int idx = hi;
        { float ov = dppf<ROW_ROR8>(v); int oi = dppi<ROW_ROR8>(idx); TSEL(ov, oi) }
        { float ov = swzf<SWZ_XOR16>(v); int oi = swzi<SWZ_XOR16>(idx); TSEL(ov, oi) }
        { float ov = __shfl_xor(v, 32); int oi = __shfl_xor(idx, 32); TSEL(ov, oi) }
        tag = idx;
    }
    if (l == 0) out[(size_t)b * T_ + (T_ - 1)] = tag;
    __syncthreads();

    for (int t0b = T_ - 16; t0b >= 0; t0b -= 16) {
        unsigned int pk[16];
#pragma unroll
        for (int qq = 0; qq < 16; ++qq) pk[qq] = hist_l[t0b + qq];
#pragma unroll
        for (int qq = 15; qq >= 0; --qq) {
            int t = t0b + qq;
            if (t >= 1) {
                tag = (pk[qq] >> (3 * tag)) & 7;
                if (l == 0) out[(size_t)b * T_ + t - 1] = tag;
            }
        }
    }
#undef TSEL
#undef VSTEPA
#undef VSTEPB
#undef LOADSUB
#undef PROC8
}

extern "C" void kernel_launch(void* const* d_in, const int* in_sizes, int n_in,
                              void* d_out, int out_size, void* d_ws, size_t ws_size,
                              hipStream_t stream) {
    (void)in_sizes; (void)n_in; (void)out_size; (void)ws_size;
    const int*   x      = (const int*)  d_in[0];
    const float* emb    = (const float*)d_in[1];
    const float* Wih_f  = (const float*)d_in[2];
    const float* Whh_f  = (const float*)d_in[3];
    const float* b_f    = (const float*)d_in[4];
    const float* Wih_b  = (const float*)d_in[5];
    const float* Whh_b  = (const float*)d_in[6];
    const float* b_b    = (const float*)d_in[7];
    const float* fcW    = (const float*)d_in[8];
    const float* fcb    = (const float*)d_in[9];
    const float* startt = (const float*)d_in[10];
    const float* endt   = (const float*)d_in[11];
    const float* trans  = (const float*)d_in[12];

    float* proj = (float*)d_ws;                    // 2*32*512 floats = 128 KB
    float* part = proj + 2 * V_ * G_;              // 2*1024*64*8 floats = 4 MB
    int*   out  = (int*)d_out;

    proj_kernel<<<64, 512, 0, stream>>>(emb, Wih_f, b_f, Wih_b, b_b, proj);
    lstm_kernel<<<128, 1024, 0, stream>>>(x, Whh_f, Whh_b, proj, fcW, part);
    viterbi_kernel<<<64, 64, 0, stream>>>(part, fcb, startt, endt, trans, out);
}